// Round 2
// baseline (3870.147 us; speedup 1.0000x reference)
//
#include <hip/hip_runtime.h>
#include <hip/hip_bf16.h>
#include <hip/hip_cooperative_groups.h>

namespace cg = cooperative_groups;

// ---------------- problem constants ----------------
constexpr int N_NODE = 4096;
constexpr int DIM    = 512;
constexpr int HID    = 256;
constexpr int NCLS   = 32;
constexpr int N_EDGE = 131072;
constexpr float ALPHA_C = 0.85f;
constexpr float EPS_C   = 1e-8f;
constexpr int N_ITER_SPMV = 49;   // + 1 init application = 50 total; err <= 0.85^50 * max|L|

constexpr int NBLK = 512;         // grid: 512 blocks x 256 threads = 131072 threads
constexpr int NTHR = 256;

// ---------------- workspace layout (bytes) ----------------
constexpr size_t OFF_BITMAP  = 0x000000;  // 2 MB   (4096*4096 bits) dedup, zeroed in P0
constexpr size_t OFF_ROWCNT  = 0x200000;  // 16 KB  per-row nnz count, zeroed
constexpr size_t OFF_DIAGEX  = 0x204000;  // 16 KB  self-loop exists flag, zeroed
constexpr size_t OFF_CNT     = 0x208000;  // counters: [0]=nnz, zeroed
constexpr size_t OFF_LOGITS  = 0x210000;  // 512 KB
constexpr size_t OFF_F       = 0x290000;  // 512 KB (normalized logits)
constexpr size_t OFF_DIAGSIM = 0x310000;  // 16 KB
constexpr size_t OFF_ROWPTR  = 0x314000;  // 4097 ints
constexpr size_t OFF_ROWNEXT = 0x31C000;  // 16 KB
constexpr size_t OFF_TR_R    = 0x320000;  // 512 KB
constexpr size_t OFF_TR_C    = 0x3A0000;  // 512 KB
constexpr size_t OFF_TR_V    = 0x420000;  // 512 KB
constexpr size_t OFF_CSRCOL  = 0x4A0000;  // 512 KB
constexpr size_t OFF_CSRVAL  = 0x520000;  // 512 KB
constexpr size_t OFF_PDIAG   = 0x5A0000;  // 16 KB  (alpha * P diagonal)
constexpr size_t OFF_BUFA    = 0x5A4000;  // 512 KB
constexpr size_t OFF_BUFB    = 0x624000;  // 512 KB

struct Params {
    const float* attr;
    const int*   row;
    const int*   col;
    const float* W0;
    const float* b0;
    const float* W1;
    const float* b1;
    float*       out;
    char*        ws;
};

// One cooperative mega-kernel. Phases separated by grid.sync():
//   P0: zero dedup/count state + fp32 MLP (logits, normalized f)
//   P1: edge sims + dedup bitmap + row counts (triples)
//   P2: prefix scan of row counts (block 0)
//   P3: scatter triples -> CSR
//   P4: per-row normalize/exp -> alpha*P; init Y0 = (1-a)L
//   P5: 49x SpMV iterations  Y <- (1-a)L + aP*Y
__global__ __launch_bounds__(NTHR, 2) void mega_kernel(Params p)
{
    cg::grid_group grid = cg::this_grid();

    const int t = threadIdx.x;
    const int b = blockIdx.x;
    const int g = b * NTHR + t;          // 0 .. 131071

    char* ws = p.ws;
    unsigned int* bitmap   = (unsigned int*)(ws + OFF_BITMAP);
    int*   row_count = (int*)(ws + OFF_ROWCNT);
    int*   diag_ex   = (int*)(ws + OFF_DIAGEX);
    int*   cnt       = (int*)(ws + OFF_CNT);
    float* logits    = (float*)(ws + OFF_LOGITS);
    float* f         = (float*)(ws + OFF_F);
    float* diag_sim  = (float*)(ws + OFF_DIAGSIM);
    int*   row_ptr   = (int*)(ws + OFF_ROWPTR);
    int*   row_next  = (int*)(ws + OFF_ROWNEXT);
    int*   tr_r      = (int*)(ws + OFF_TR_R);
    int*   tr_c      = (int*)(ws + OFF_TR_C);
    float* tr_v      = (float*)(ws + OFF_TR_V);
    int*   csr_col   = (int*)(ws + OFF_CSRCOL);
    float* csr_val   = (float*)(ws + OFF_CSRVAL);
    float* pdiag     = (float*)(ws + OFF_PDIAG);
    float* bufA      = (float*)(ws + OFF_BUFA);
    float* bufB      = (float*)(ws + OFF_BUFB);

    __shared__ __align__(16) float attr_s[8 * DIM];   // 16 KB
    __shared__ __align__(16) float x_s[8 * HID];      // 8 KB
    __shared__ int scan_s[NTHR];                      // 1 KB

    // ================= P0a: zero the state the harness poisoned =================
    {
        uint4 z4 = make_uint4(0u, 0u, 0u, 0u);
        ((uint4*)bitmap)[g] = z4;                 // 131072 * 16 B = 2 MB exactly
        if (g < N_NODE) { row_count[g] = 0; diag_ex[g] = 0; }
        if (g < 8)      cnt[g] = 0;
    }

    // ================= P0b: MLP (fp32; threshold semantics fragile in bf16) ====
    {
        const int node0 = b * 8;
        const float* ap = p.attr + (size_t)node0 * DIM;
        for (int i = t; i < 8 * DIM; i += NTHR) attr_s[i] = ap[i];
        __syncthreads();

        // hidden layer: 2 node-groups x 128 threads; thread = 2 hidden units x 4 nodes
        const int pg = t >> 7;               // node-group 0/1
        const int hh = (t & 127) * 2;        // hidden pair base
        const float2 b0v = *(const float2*)(p.b0 + hh);
        float acc0[4], acc1[4];
#pragma unroll
        for (int n = 0; n < 4; n++) { acc0[n] = b0v.x; acc1[n] = b0v.y; }

        for (int k = 0; k < DIM; k += 4) {
            const float2 w0 = *(const float2*)(p.W0 + (k + 0) * HID + hh);
            const float2 w1 = *(const float2*)(p.W0 + (k + 1) * HID + hh);
            const float2 w2 = *(const float2*)(p.W0 + (k + 2) * HID + hh);
            const float2 w3 = *(const float2*)(p.W0 + (k + 3) * HID + hh);
#pragma unroll
            for (int n = 0; n < 4; n++) {
                const float4 a = *(const float4*)(attr_s + (4 * pg + n) * DIM + k);
                acc0[n] = fmaf(a.x, w0.x, acc0[n]); acc1[n] = fmaf(a.x, w0.y, acc1[n]);
                acc0[n] = fmaf(a.y, w1.x, acc0[n]); acc1[n] = fmaf(a.y, w1.y, acc1[n]);
                acc0[n] = fmaf(a.z, w2.x, acc0[n]); acc1[n] = fmaf(a.z, w2.y, acc1[n]);
                acc0[n] = fmaf(a.w, w3.x, acc0[n]); acc1[n] = fmaf(a.w, w3.y, acc1[n]);
            }
        }
#pragma unroll
        for (int n = 0; n < 4; n++) {
            x_s[(4 * pg + n) * HID + hh]     = fmaxf(acc0[n], 0.0f);
            x_s[(4 * pg + n) * HID + hh + 1] = fmaxf(acc1[n], 0.0f);
        }
        __syncthreads();

        // output layer: thread -> node t>>5, class t&31
        const int n = t >> 5, c = t & 31;
        float lg = p.b1[c];
        for (int k = 0; k < HID; k += 4) {
            const float4 x4 = *(const float4*)(x_s + n * HID + k);
            lg = fmaf(x4.x, p.W1[(k + 0) * NCLS + c], lg);
            lg = fmaf(x4.y, p.W1[(k + 1) * NCLS + c], lg);
            lg = fmaf(x4.z, p.W1[(k + 2) * NCLS + c], lg);
            lg = fmaf(x4.w, p.W1[(k + 3) * NCLS + c], lg);
        }
        float sq = lg * lg;
#pragma unroll
        for (int m = 16; m >= 1; m >>= 1) sq += __shfl_xor(sq, m, 32);
        const float nr = fmaxf(sqrtf(sq), EPS_C);
        const int r = node0 + n;
        logits[r * NCLS + c] = lg;
        f[r * NCLS + c] = lg / nr;
    }

    grid.sync();

    // ================= P1: edge sims + dedup + row counts ======================
    {
        const int e = g;                     // exactly N_EDGE threads
        const int r = p.row[e], c = p.col[e];
        const float4* fr = (const float4*)(f + r * NCLS);
        const float4* fc = (const float4*)(f + c * NCLS);
        float sim = 0.f;
#pragma unroll
        for (int q = 0; q < 8; q++) {
            float4 a = fr[q], bb = fc[q];
            sim += a.x * bb.x + a.y * bb.y + a.z * bb.z + a.w * bb.w;
        }
        if (sim >= 0.1f) {                   // where(sim<0.1, 0, sim): zero == absent
            if (r == c) {
                diag_ex[r] = 1;              // dup writes are identical values
                diag_sim[r] = sim;
            } else {
                // dedup: .at[r,c].set counts a cell ONCE even with duplicate edges
                unsigned int bit = (unsigned int)r * N_NODE + (unsigned int)c;
                unsigned int w = bit >> 5, m = 1u << (bit & 31);
                unsigned int old = atomicOr(&bitmap[w], m);
                if (!(old & m)) {
                    int idx = atomicAdd(cnt, 1);
                    tr_r[idx] = r; tr_c[idx] = c; tr_v[idx] = sim;
                    atomicAdd(&row_count[r], 1);
                }
            }
        }
    }

    grid.sync();

    // ================= P2: exclusive prefix scan (block 0 only) ================
    if (b == 0) {
        int v[16], sum = 0;
#pragma unroll
        for (int i = 0; i < 16; i++) { v[i] = row_count[t * 16 + i]; sum += v[i]; }
        scan_s[t] = sum;
        __syncthreads();
        for (int off = 1; off < NTHR; off <<= 1) {
            int x = (t >= off) ? scan_s[t - off] : 0;
            __syncthreads();
            scan_s[t] += x;
            __syncthreads();
        }
        int excl = scan_s[t] - sum;
#pragma unroll
        for (int i = 0; i < 16; i++) {
            row_ptr[t * 16 + i] = excl; row_next[t * 16 + i] = excl; excl += v[i];
        }
        if (t == NTHR - 1) row_ptr[N_NODE] = scan_s[NTHR - 1];
    }

    grid.sync();

    // ================= P3: scatter triples into CSR ============================
    {
        const int nnz = cnt[0];
        if (g < nnz) {
            const int r = tr_r[g];
            int pos = atomicAdd(&row_next[r], 1);
            csr_col[pos] = tr_c[g];
            csr_val[pos] = tr_v[g];
        }
    }

    grid.sync();

    // ================= P4: per-row normalize + exp -> alpha*P; init Y0 =========
    const int r = g >> 5;       // row owned by this 32-lane group
    const int c = g & 31;       // class / column
    {
        // global flags from S[0,0] (every thread computes; cached reads)
        const float S00 = diag_ex[0] ? diag_sim[0] : 0.0f;
        const int rm  = (S00 == 1.0f) ? 1 : 0;            // remove diagonal?
        const float d_eff0 = rm ? 0.0f : S00;
        const int add = (d_eff0 == 0.0f) ? 1 : 0;         // add diag(lam)?

        const int s = row_ptr[r], e = row_ptr[r + 1];
        const float d = diag_ex[r] ? diag_sim[r] : 0.0f;
        const float d_eff = rm ? 0.0f : d;

        float part = 0.0f;
        for (int j = s + c; j < e; j += 32) part += csr_val[j];
#pragma unroll
        for (int m = 16; m >= 1; m >>= 1) part += __shfl_xor(part, m, 32);
        const float rowsum = d_eff + part;
        const float denom = (rowsum == 0.0f) ? 1.0f : rowsum;
        const float sn_d = d_eff / denom;
        const int degree = (e - s) + ((sn_d != 0.0f) ? 1 : 0);   // count(Sn != 0)
        const float lam = 1.0f / (float)(degree + 1);
        const float diag_final = sn_d + (add ? lam : 0.0f);
        const float a_d = (diag_final != 0.0f) ? expf(diag_final) : 0.0f;

        float dpart = 0.0f;
        for (int j = s + c; j < e; j += 32) dpart += expf(csr_val[j] / denom);
#pragma unroll
        for (int m = 16; m >= 1; m >>= 1) dpart += __shfl_xor(dpart, m, 32);
        const float degA = a_d + dpart;
        const float inv = 1.0f / fmaxf(degA, EPS_C);

        if (c == 0) pdiag[r] = ALPHA_C * a_d * inv;
        for (int j = s + c; j < e; j += 32)
            csr_val[j] = ALPHA_C * expf(csr_val[j] / denom) * inv;

        bufA[g] = (1.0f - ALPHA_C) * logits[g];           // Y0 = (1-a)L
    }

    // ================= P5: 49x SpMV  Y <- (1-a)L + aP*Y ========================
    {
        const float base = (1.0f - ALPHA_C) * logits[g];  // held in regs all iters
        const int s = row_ptr[r], e = row_ptr[r + 1];
        const float pd = pdiag[r];   // note: written by lane c==0 of OUR group in P4,
                                     // but needs grid visibility -> read after sync below

        float* bufs[2] = { bufA, bufB };
        float pd_local = pd;
        for (int it = 0; it < N_ITER_SPMV; ++it) {
            grid.sync();
            if (it == 0) pd_local = pdiag[r];             // re-read after first sync
            const float* src = bufs[it & 1];
            float* dst = (it == N_ITER_SPMV - 1) ? p.out : bufs[(it + 1) & 1];
            float acc = base + pd_local * src[g];
            for (int j = s; j < e; j++)
                acc = fmaf(csr_val[j], src[csr_col[j] * NCLS + c], acc);
            dst[g] = acc;
        }
    }
}

// ---------------- launch ----------------
extern "C" void kernel_launch(void* const* d_in, const int* in_sizes, int n_in,
                              void* d_out, int out_size, void* d_ws, size_t ws_size,
                              hipStream_t stream)
{
    Params prm;
    prm.attr = (const float*)d_in[0];
    prm.row  = (const int*)d_in[1];
    prm.col  = (const int*)d_in[2];
    prm.W0   = (const float*)d_in[3];
    prm.b0   = (const float*)d_in[4];
    prm.W1   = (const float*)d_in[5];
    prm.b1   = (const float*)d_in[6];
    prm.out  = (float*)d_out;
    prm.ws   = (char*)d_ws;

    void* args[] = { &prm };
    hipLaunchCooperativeKernel((void*)mega_kernel, dim3(NBLK), dim3(NTHR),
                               args, 0, stream);
}

// Round 3
// 3193.780 us; speedup vs baseline: 1.2118x; 1.2118x over previous
//
#include <hip/hip_runtime.h>
#include <hip/hip_bf16.h>

// ---------------- problem constants ----------------
constexpr int N_NODE = 4096;
constexpr int DIM    = 512;
constexpr int HID    = 256;
constexpr int NCLS   = 32;
constexpr int N_EDGE = 131072;
constexpr float ALPHA_C = 0.85f;
constexpr float EPS_C   = 1e-8f;
constexpr int N_ITER_SPMV = 49;   // + init = 50 applications; err <= 0.85^50 * |L|max

// ---------------- workspace layout (bytes) ----------------
// zeroed region (one memsetAsync): [0, 0x208200)
constexpr size_t OFF_BITMAP  = 0x000000;  // 2 MB   (4096*4096 bits) dedup
constexpr size_t OFF_ROWCNT  = 0x200000;  // 16 KB  per-row nnz count
constexpr size_t OFF_DIAGEX  = 0x204000;  // 16 KB  self-loop exists flag
constexpr size_t OFF_CNT     = 0x208000;  // [0]=nnz
constexpr size_t ZERO_BYTES  = 0x208200;
// non-zeroed
constexpr size_t OFF_LOGITS  = 0x210000;  // 512 KB
constexpr size_t OFF_F       = 0x290000;  // 512 KB (normalized logits)
constexpr size_t OFF_DIAGSIM = 0x310000;  // 16 KB
constexpr size_t OFF_ROWPTR  = 0x314000;  // 4097 ints
constexpr size_t OFF_ROWNEXT = 0x31C000;  // 16 KB
constexpr size_t OFF_TR_R    = 0x320000;  // 512 KB
constexpr size_t OFF_TR_C    = 0x3A0000;  // 512 KB
constexpr size_t OFF_TR_V    = 0x420000;  // 512 KB
constexpr size_t OFF_CSRCV   = 0x4A0000;  // 1 MB  packed {col, val} int2
constexpr size_t OFF_PDIAG   = 0x5A0000;  // 16 KB (alpha * P diagonal)

// ---------------- K1: MLP + logits + normalized f (fp32) ----------------
// 8 nodes/block, 256 threads; thread = 2 hidden units x 4 nodes (halves LDS reads
// vs 1 unit/thread). fp32 throughout: bf16 would flip ~2.5K sims across the 0.1
// threshold (sim pdf ~1.9/unit at 0.1) -> >1e-2 output error.
__global__ __launch_bounds__(256) void mlp_kernel(
    const float* __restrict__ attr, const float* __restrict__ W0,
    const float* __restrict__ b0, const float* __restrict__ W1,
    const float* __restrict__ b1, float* __restrict__ logits,
    float* __restrict__ f)
{
    __shared__ __align__(16) float attr_s[8 * DIM];   // 16 KB
    __shared__ __align__(16) float x_s[8 * HID];      // 8 KB
    const int t = threadIdx.x;
    const int node0 = blockIdx.x * 8;
    const float* ap = attr + (size_t)node0 * DIM;
    for (int i = t; i < 8 * DIM; i += 256) attr_s[i] = ap[i];
    __syncthreads();

    const int pg = t >> 7;               // node-group 0/1
    const int hh = (t & 127) * 2;        // hidden pair base
    const float2 b0v = *(const float2*)(b0 + hh);
    float acc0[4], acc1[4];
#pragma unroll
    for (int n = 0; n < 4; n++) { acc0[n] = b0v.x; acc1[n] = b0v.y; }

    for (int k = 0; k < DIM; k += 4) {
        const float2 w0 = *(const float2*)(W0 + (k + 0) * HID + hh);
        const float2 w1 = *(const float2*)(W0 + (k + 1) * HID + hh);
        const float2 w2 = *(const float2*)(W0 + (k + 2) * HID + hh);
        const float2 w3 = *(const float2*)(W0 + (k + 3) * HID + hh);
#pragma unroll
        for (int n = 0; n < 4; n++) {
            const float4 a = *(const float4*)(attr_s + (4 * pg + n) * DIM + k);
            acc0[n] = fmaf(a.x, w0.x, acc0[n]); acc1[n] = fmaf(a.x, w0.y, acc1[n]);
            acc0[n] = fmaf(a.y, w1.x, acc0[n]); acc1[n] = fmaf(a.y, w1.y, acc1[n]);
            acc0[n] = fmaf(a.z, w2.x, acc0[n]); acc1[n] = fmaf(a.z, w2.y, acc1[n]);
            acc0[n] = fmaf(a.w, w3.x, acc0[n]); acc1[n] = fmaf(a.w, w3.y, acc1[n]);
        }
    }
#pragma unroll
    for (int n = 0; n < 4; n++) {
        x_s[(4 * pg + n) * HID + hh]     = fmaxf(acc0[n], 0.0f);
        x_s[(4 * pg + n) * HID + hh + 1] = fmaxf(acc1[n], 0.0f);
    }
    __syncthreads();

    const int n = t >> 5, c = t & 31;
    float lg = b1[c];
    for (int k = 0; k < HID; k += 4) {
        const float4 x4 = *(const float4*)(x_s + n * HID + k);
        lg = fmaf(x4.x, W1[(k + 0) * NCLS + c], lg);
        lg = fmaf(x4.y, W1[(k + 1) * NCLS + c], lg);
        lg = fmaf(x4.z, W1[(k + 2) * NCLS + c], lg);
        lg = fmaf(x4.w, W1[(k + 3) * NCLS + c], lg);
    }
    float sq = lg * lg;
#pragma unroll
    for (int m = 16; m >= 1; m >>= 1) sq += __shfl_xor(sq, m, 32);
    const float nr = fmaxf(sqrtf(sq), EPS_C);
    const int r = node0 + n;
    logits[r * NCLS + c] = lg;
    f[r * NCLS + c] = lg / nr;
}

// ---------------- K2: edge sims + dedup + row counts ----------------
__global__ __launch_bounds__(256) void edge_kernel(
    const int* __restrict__ row, const int* __restrict__ col,
    const float* __restrict__ f, unsigned int* __restrict__ bitmap,
    int* __restrict__ row_count, int* __restrict__ tr_r,
    int* __restrict__ tr_c, float* __restrict__ tr_v,
    float* __restrict__ diag_sim, int* __restrict__ diag_ex,
    int* __restrict__ nnz_counter)
{
    const int e = blockIdx.x * blockDim.x + threadIdx.x;
    const int r = row[e], c = col[e];
    const float4* fr = (const float4*)(f + r * NCLS);
    const float4* fc = (const float4*)(f + c * NCLS);
    float sim = 0.f;
#pragma unroll
    for (int q = 0; q < 8; q++) {
        float4 a = fr[q], b = fc[q];
        sim += a.x * b.x + a.y * b.y + a.z * b.z + a.w * b.w;
    }
    if (sim < 0.1f) return;  // where(sim<0.1, 0, sim): zero == absent cell
    if (r == c) {
        diag_ex[r] = 1;                  // dup writes are identical values
        diag_sim[r] = sim;
    } else {
        // dedup: .at[r,c].set counts a cell ONCE even with duplicate edges
        unsigned int bit = (unsigned int)r * N_NODE + (unsigned int)c;
        unsigned int w = bit >> 5, m = 1u << (bit & 31);
        unsigned int old = atomicOr(&bitmap[w], m);
        if (!(old & m)) {
            int idx = atomicAdd(nnz_counter, 1);
            tr_r[idx] = r; tr_c[idx] = c; tr_v[idx] = sim;
            atomicAdd(&row_count[r], 1);
        }
    }
}

// ---------------- K3: exclusive prefix scan of 4096 row counts ----------------
__global__ __launch_bounds__(1024) void scan_kernel(
    const int* __restrict__ row_count, int* __restrict__ row_ptr,
    int* __restrict__ row_next)
{
    __shared__ int s[1024];
    const int t = threadIdx.x;
    int v0 = row_count[t * 4 + 0], v1 = row_count[t * 4 + 1];
    int v2 = row_count[t * 4 + 2], v3 = row_count[t * 4 + 3];
    int sum = v0 + v1 + v2 + v3;
    s[t] = sum;
    __syncthreads();
    for (int off = 1; off < 1024; off <<= 1) {
        int x = (t >= off) ? s[t - off] : 0;
        __syncthreads();
        s[t] += x;
        __syncthreads();
    }
    int excl = s[t] - sum;
    row_ptr[t * 4 + 0] = excl; row_next[t * 4 + 0] = excl; excl += v0;
    row_ptr[t * 4 + 1] = excl; row_next[t * 4 + 1] = excl; excl += v1;
    row_ptr[t * 4 + 2] = excl; row_next[t * 4 + 2] = excl; excl += v2;
    row_ptr[t * 4 + 3] = excl; row_next[t * 4 + 3] = excl; excl += v3;
    if (t == 1023) row_ptr[4096] = s[1023];
}

// ---------------- K4: scatter triples into packed CSR {col,val} ----------------
__global__ __launch_bounds__(256) void scatter_kernel(
    const int* __restrict__ tr_r, const int* __restrict__ tr_c,
    const float* __restrict__ tr_v, const int* __restrict__ nnz_counter,
    int* __restrict__ row_next, int2* __restrict__ csr_cv)
{
    const int i = blockIdx.x * blockDim.x + threadIdx.x;
    if (i >= nnz_counter[0]) return;
    const int r = tr_r[i];
    int pos = atomicAdd(&row_next[r], 1);
    csr_cv[pos] = make_int2(tr_c[i], __float_as_int(tr_v[i]));
}

// ---------------- K5: per-row normalize + exp -> alpha*P (flags inline) --------
__global__ __launch_bounds__(256) void finalize_kernel(
    const int* __restrict__ row_ptr, int2* __restrict__ csr_cv,
    const int* __restrict__ diag_ex, const float* __restrict__ diag_sim,
    float* __restrict__ pdiag)
{
    const int r = blockIdx.x * blockDim.x + threadIdx.x;
    // global flags from S[0,0] (broadcast L2 reads, every thread)
    const float S00 = diag_ex[0] ? diag_sim[0] : 0.0f;
    const int rm  = (S00 == 1.0f) ? 1 : 0;            // remove diagonal?
    const float d_eff0 = rm ? 0.0f : S00;
    const int add = (d_eff0 == 0.0f) ? 1 : 0;         // add diag(lam)?

    const int s = row_ptr[r], e = row_ptr[r + 1];
    const float d = diag_ex[r] ? diag_sim[r] : 0.0f;
    const float d_eff = rm ? 0.0f : d;
    float rowsum = d_eff;                              // all vals >= 0.1 > 0
    for (int j = s; j < e; j++) rowsum += __int_as_float(csr_cv[j].y);
    const float denom = (rowsum == 0.0f) ? 1.0f : rowsum;
    const float sn_d = d_eff / denom;
    const int degree = (e - s) + ((sn_d != 0.0f) ? 1 : 0);  // count(Sn != 0)
    const float lam = 1.0f / (float)(degree + 1);
    const float diag_final = sn_d + (add ? lam : 0.0f);
    const float a_d = (diag_final != 0.0f) ? expf(diag_final) : 0.0f;
    float degA = a_d;
    for (int j = s; j < e; j++) degA += expf(__int_as_float(csr_cv[j].y) / denom);
    const float inv = 1.0f / fmaxf(degA, EPS_C);
    pdiag[r] = ALPHA_C * a_d * inv;
    for (int j = s; j < e; j++) {
        float v = __int_as_float(csr_cv[j].y);
        csr_cv[j].y = __float_as_int(ALPHA_C * expf(v / denom) * inv);
    }
}

// ---------------- K6: LDS-resident Jacobi solve, one column per block ----------
// Key: Y <- (1-a)L + aP*Y never mixes columns. Block b owns column b; its
// 4096-row slice (16 KB) lives in LDS double-buffered. 49 iterations with only
// __syncthreads() -- zero grid syncs, zero launches for the whole propagation.
__global__ __launch_bounds__(512) void solve_kernel(
    const float* __restrict__ logits, const int* __restrict__ row_ptr,
    const int2* __restrict__ csr_cv, const float* __restrict__ pdiag,
    float* __restrict__ out)
{
    __shared__ float Y[2][N_NODE];        // 32 KB
    const int t = threadIdx.x;            // 512 threads, 8 rows each (contiguous
    const int c = blockIdx.x;             //  -> coalesced-ish CSR segments)
    const int r0 = t * 8;

    float base[8], pd[8];
    int rp[9];
#pragma unroll
    for (int i = 0; i < 9; i++) rp[i] = row_ptr[r0 + i];
#pragma unroll
    for (int i = 0; i < 8; i++) {
        base[i] = (1.0f - ALPHA_C) * logits[(r0 + i) * NCLS + c];
        pd[i]   = pdiag[r0 + i];
        Y[0][r0 + i] = base[i];           // Y0 = (1-a)L
    }
    __syncthreads();

    for (int it = 0; it < N_ITER_SPMV; ++it) {
        const float* __restrict__ src = Y[it & 1];
        float* __restrict__ dst = Y[(it + 1) & 1];
#pragma unroll
        for (int i = 0; i < 8; i++) {
            float acc = fmaf(pd[i], src[r0 + i], base[i]);
            for (int j = rp[i]; j < rp[i + 1]; ++j) {
                const int2 cv = csr_cv[j];          // one dwordx2 from L2
                acc = fmaf(__int_as_float(cv.y), src[cv.x], acc);  // LDS gather
            }
            dst[r0 + i] = acc;
        }
        __syncthreads();
    }
    const float* fin = Y[N_ITER_SPMV & 1];
#pragma unroll
    for (int i = 0; i < 8; i++)
        out[(r0 + i) * NCLS + c] = fin[r0 + i];
}

// ---------------- launch ----------------
extern "C" void kernel_launch(void* const* d_in, const int* in_sizes, int n_in,
                              void* d_out, int out_size, void* d_ws, size_t ws_size,
                              hipStream_t stream)
{
    const float* attr = (const float*)d_in[0];
    const int*   row  = (const int*)d_in[1];
    const int*   col  = (const int*)d_in[2];
    const float* W0   = (const float*)d_in[3];
    const float* b0   = (const float*)d_in[4];
    const float* W1   = (const float*)d_in[5];
    const float* b1   = (const float*)d_in[6];
    float* out = (float*)d_out;

    char* ws = (char*)d_ws;
    unsigned int* bitmap = (unsigned int*)(ws + OFF_BITMAP);
    int*   row_count = (int*)(ws + OFF_ROWCNT);
    int*   diag_ex   = (int*)(ws + OFF_DIAGEX);
    int*   cnt       = (int*)(ws + OFF_CNT);
    float* logits    = (float*)(ws + OFF_LOGITS);
    float* f         = (float*)(ws + OFF_F);
    float* diag_sim  = (float*)(ws + OFF_DIAGSIM);
    int*   row_ptr   = (int*)(ws + OFF_ROWPTR);
    int*   row_next  = (int*)(ws + OFF_ROWNEXT);
    int*   tr_r      = (int*)(ws + OFF_TR_R);
    int*   tr_c      = (int*)(ws + OFF_TR_C);
    float* tr_v      = (float*)(ws + OFF_TR_V);
    int2*  csr_cv    = (int2*)(ws + OFF_CSRCV);
    float* pdiag     = (float*)(ws + OFF_PDIAG);

    hipMemsetAsync(ws, 0, ZERO_BYTES, stream);

    mlp_kernel<<<N_NODE / 8, 256, 0, stream>>>(attr, W0, b0, W1, b1, logits, f);
    edge_kernel<<<N_EDGE / 256, 256, 0, stream>>>(row, col, f, bitmap, row_count,
                                                  tr_r, tr_c, tr_v, diag_sim,
                                                  diag_ex, cnt);
    scan_kernel<<<1, 1024, 0, stream>>>(row_count, row_ptr, row_next);
    scatter_kernel<<<N_EDGE / 256, 256, 0, stream>>>(tr_r, tr_c, tr_v, cnt,
                                                     row_next, csr_cv);
    finalize_kernel<<<N_NODE / 256, 256, 0, stream>>>(row_ptr, csr_cv, diag_ex,
                                                      diag_sim, pdiag);
    solve_kernel<<<NCLS, 512, 0, stream>>>(logits, row_ptr, csr_cv, pdiag, out);
}